// Round 2
// baseline (1021.261 us; speedup 1.0000x reference)
//
#include <hip/hip_runtime.h>
#include <hip/hip_cooperative_groups.h>
#include <math.h>

#define BB 8
#define TT 128
#define NN 512
#define HH 4
#define DD 2048      // N*HID
#define EE 16384
#define KTOT 4096    // 2048 (x) + 2048 (h)
#define NKB 128      // KTOT/32 kblocks
#define XROW 4112    // 4096 + 16 pad shorts (32 B) per batch row in LDS
#define SENT 0xFFFFFFFFu

typedef __attribute__((ext_vector_type(8))) short short8;
typedef __attribute__((ext_vector_type(4))) float f32x4;

__device__ __forceinline__ float b2f(unsigned short u) {
    union { unsigned int i; float f; } v; v.i = ((unsigned int)u) << 16; return v.f;
}
__device__ __forceinline__ unsigned short f2b(float f) {
    union { float f; unsigned int i; } v; v.f = f;
    unsigned int r = v.i + 0x7fff + ((v.i >> 16) & 1);
    return (unsigned short)(r >> 16);
}
// fast sigmoid/tanh on v_exp_f32 + v_rcp_f32 (~4 ULP; absmax budget 0.0117)
__device__ __forceinline__ float fsig(float z) {
    return __builtin_amdgcn_rcpf(1.f + __expf(-z));
}
__device__ __forceinline__ float ftanh(float z) {
    return 1.f - 2.f * __builtin_amdgcn_rcpf(1.f + __expf(2.f * z));
}

// ---------------- CSR build (edges identical every timestep) ----------------

__global__ void k_csr_zero(int* __restrict__ counts, int* __restrict__ fill) {
    int i = threadIdx.x;
    counts[i] = 0;
    fill[i] = 0;
}

__global__ void k_csr_count(const int* __restrict__ ei, int* __restrict__ counts) {
    int e = blockIdx.x * blockDim.x + threadIdx.x;
    if (e < EE) atomicAdd(&counts[ei[EE + e]], 1);
}

__global__ void k_csr_scan(const int* __restrict__ counts, int* __restrict__ offs) {
    __shared__ int s[NN];
    const int i = threadIdx.x;
    s[i] = counts[i];
    __syncthreads();
#pragma unroll
    for (int off = 1; off < NN; off <<= 1) {
        int v = (i >= off) ? s[i - off] : 0;
        __syncthreads();
        s[i] += v;
        __syncthreads();
    }
    offs[i + 1] = s[i];
    if (i == 0) offs[0] = 0;
}

__global__ void k_csr_fill(const int* __restrict__ ei, const int* __restrict__ offs,
                           int* __restrict__ fill, int* __restrict__ csr_src) {
    int e = blockIdx.x * blockDim.x + threadIdx.x;
    if (e < EE) {
        int d = ei[EE + e];
        int pos = atomicAdd(&fill[d], 1);
        csr_src[offs[d] + pos] = ei[e];
    }
}

// ---------------- GAT (outputs bf16 seq[t][b][d]) ----------------

__global__ void k_gat0(const float* __restrict__ xseq, const float* __restrict__ W,
                       const float* __restrict__ as, const float* __restrict__ ad,
                       const float* __restrict__ bias, const int* __restrict__ offs,
                       const int* __restrict__ csr_src, unsigned short* __restrict__ seqout) {
    __shared__ float xr[NN];
    const int t = blockIdx.x;
    const int j = threadIdx.x;
    xr[j] = xseq[t * NN + j];
    __syncthreads();

    const float w0 = W[0], w1 = W[1], w2 = W[2], w3 = W[3];
    const float cs = w0 * as[0] + w1 * as[1] + w2 * as[2] + w3 * as[3];
    const float cd = w0 * ad[0] + w1 * ad[1] + w2 * ad[2] + w3 * ad[3];

    const float xj = xr[j];
    const float ed = cd * xj;
    float e0 = (cs + cd) * xj;
    e0 = e0 > 0.f ? e0 : 0.2f * e0;

    const int s0 = offs[j], s1 = offs[j + 1];
    float m = e0;
    for (int p = s0; p < s1; ++p) {
        float e = cs * xr[csr_src[p]] + ed;
        e = e > 0.f ? e : 0.2f * e;
        m = fmaxf(m, e);
    }
    float den = expf(e0 - m);
    float num = den * xj;
    for (int p = s0; p < s1; ++p) {
        int s = csr_src[p];
        float e = cs * xr[s] + ed;
        e = e > 0.f ? e : 0.2f * e;
        float wgt = expf(e - m);
        den += wgt;
        num += wgt * xr[s];
    }
    const float y = num / den;

    ushort4 o;
    o.x = f2b(fmaxf(w0 * y + bias[0], 0.f));
    o.y = f2b(fmaxf(w1 * y + bias[1], 0.f));
    o.z = f2b(fmaxf(w2 * y + bias[2], 0.f));
    o.w = f2b(fmaxf(w3 * y + bias[3], 0.f));
    *(ushort4*)(seqout + (size_t)t * BB * DD + (size_t)j * HH) = o;
}

__global__ void k_gat_rest(const float* __restrict__ xseq, const float* __restrict__ W,
                           const float* __restrict__ bias, unsigned short* __restrict__ seqout) {
    int n = blockIdx.x * blockDim.x + threadIdx.x;
    int t = n / (7 * NN);
    int rem = n - t * (7 * NN);
    int b = 1 + rem / NN;
    int j = rem - (b - 1) * NN;
    float x = xseq[((size_t)b * TT + t) * NN + j];
    const float w0 = W[0], w1 = W[1], w2 = W[2], w3 = W[3];
    ushort4 o;
    o.x = f2b(fmaxf(w0 * x + bias[0], 0.f));
    o.y = f2b(fmaxf(w1 * x + bias[1], 0.f));
    o.z = f2b(fmaxf(w2 * x + bias[2], 0.f));
    o.w = f2b(fmaxf(w3 * x + bias[3], 0.f));
    *(ushort4*)(seqout + (size_t)t * BB * DD + (size_t)b * DD + (size_t)j * HH) = o;
}

// ---------------- weight pack: f32 -> bf16 B-fragment tiles ----------------
__global__ __launch_bounds__(256) void k_pack_w(const float* __restrict__ wih,
                                                const float* __restrict__ whh,
                                                unsigned short* __restrict__ WP) {
    const int pair = blockIdx.x * 4 + (threadIdx.x >> 6);  // (s,kb): 0..65535
    const int lane = threadIdx.x & 63;
    const int s = pair >> 7, kb = pair & 127;
    const int n = lane >> 2, quad = lane & 3;
    const int d = (s >> 1) * 8 + (s & 1) * 4 + (n & 3);
    const int row = (n >> 2) * 2048 + d;
    const int k = kb * 32 + quad * 8;
    const float* src = (k < 2048) ? (wih + (size_t)row * 2048 + k)
                                  : (whh + (size_t)row * 2048 + (k - 2048));
    unsigned int u[4];
#pragma unroll
    for (int p = 0; p < 4; ++p)
        u[p] = (unsigned int)f2b(src[2 * p]) | ((unsigned int)f2b(src[2 * p + 1]) << 16);
    ((uint4*)WP)[(size_t)pair * 64 + quad * 16 + n] = make_uint4(u[0], u[1], u[2], u[3]);
}

// ---------------- init h ring: X0 = zeros (S_0), X1/X2 = sentinel ----------------

__global__ void k_zero(unsigned int* __restrict__ hb) {
    int i = blockIdx.x * blockDim.x + threadIdx.x;   // 24576 dwords = 3 x 32 KB
    if (i < 3 * 8192) hb[i] = (i < 8192) ? 0u : SENT;
}

// ---------------- persistent LSTM ----------------
// 256 blocks x 1024 thr (cooperative). Block b: d0=8b..8b+7, strips 2b/2b+1.
// Cross-block h exchange: SENTINEL-IN-PAYLOAD, 3-buffer ring, NO flags, NO
// producer drain on the critical path.
//   h layout (global): hseg[block][batch][8 bf16] -> 16-B units; a finite bf16
//   pair can never be 0xFFFFFFFF, so SENT marks "not yet written".
//   Step t: consume S_t from X[t%3] (poll payload until != SENT -> the poll
//   load IS the data load), publish S_{t+1} into X[(t+1)%3], poison own
//   segment of X[(t+2)%3]. wave0's single s_waitcnt(0) orders poison before
//   publish and is hidden under ~1500 cy of gate math.
//   Soundness: a block reaches step g only after consuming all of S_{g-1};
//   every S_{g-1} publish is ordered after its owner's poison of X[g%3]
//   (step g-2), so polls at step g see sentinel-or-fresh only. And when
//   X[g%3] is poisoned at step g-2, all readers of its old data (S_{g-3},
//   read at step g-3) are provably done. Own 8 units bypass L3: wave0 writes
//   them straight into next step's LDS image (consumers self-skip).
__global__ __launch_bounds__(1024, 4) void k_lstm_persist(
    const unsigned short* __restrict__ seq, const uint4* __restrict__ WPq,
    const float* __restrict__ b_ih, const float* __restrict__ b_hh,
    unsigned int* __restrict__ hb) {
    __shared__ unsigned short xh[8][XROW];  // 65792 B unique x||h image
    __shared__ float red[2][8][32][4];      // 8 KB k-partial D
    __shared__ float biasL[32];

    const int tid = threadIdx.x;
    const int wave = tid >> 6, lane = tid & 63;
    const int st = wave >> 3, ke = wave & 7;
    const int bx = blockIdx.x;
    const int d0 = bx * 8;
    const size_t sglob = (size_t)bx * 2 + st;

    if (tid < 32) {
        const int g = tid >> 3, dl = tid & 7;
        const int row = g * 2048 + d0 + dl;
        biasL[tid] = b_ih[row] + b_hh[row];
    }

    // load this wave's 16 weight fragments into registers (once)
    uint4 w[16];
    {
        const uint4* wp = WPq + (sglob * NKB + (size_t)ke * 16) * 64 + lane;
#pragma unroll
        for (int i = 0; i < 16; ++i) w[i] = wp[i * 64];
    }

    // A-operand LDS read base for this lane: batch = lane&7, quad = lane>>4
    const unsigned short* arow = &xh[lane & 7][(lane >> 4) << 3];

    // consumer units: u0 = 2*tid (even), u1 = u0+1 (same producing block)
    const int u0 = tid << 1;
    const int blku = u0 >> 3;                 // producing block of both units
    const bool selfu = (blku == bx);

    // gate-thread state (wave 0, lane = 8*b + dl): one c cell per lane
    float creg = 0.f;

    for (int t = 0; t < TT; ++t) {
        const unsigned short* xt = seq + (size_t)t * BB * DD;
        const unsigned int* bin = hb + (size_t)(t % 3) * 8192;        // S_t
        unsigned int* bout      = hb + (size_t)((t + 1) % 3) * 8192;  // S_{t+1}
        unsigned int* bpoi      = hb + (size_t)((t + 2) % 3) * 8192;  // poison

        // stage x part (k<2048), two-phase so both 16B loads are in flight
        uint4 xv[2];
#pragma unroll
        for (int i = 0; i < 2; ++i) {
            const int c = tid + 1024 * i;            // 2048 chunks of 16 B
            xv[i] = *(const uint4*)(xt + (c >> 8) * DD + ((c & 255) << 3));
        }
#pragma unroll
        for (int i = 0; i < 2; ++i) {
            const int c = tid + 1024 * i;
            *(uint4*)&xh[c >> 8][(c & 255) << 3] = xv[i];
        }

        // h consume: poll payload (2 units = 32 B / thread). At t=0 the ring
        // holds pre-zeroed S_0 (zeros are non-sentinel -> passes instantly);
        // own-block units are skipped for t>0 (wave0 seeded them in LDS).
        if (t == 0 || !selfu) {
            const unsigned int* pu = bin + ((size_t)u0 << 2);
            unsigned int a0, a1, a2, a3, c0, c1, c2, c3;
            while (true) {
                a0 = __hip_atomic_load(pu + 0, __ATOMIC_RELAXED, __HIP_MEMORY_SCOPE_AGENT);
                a1 = __hip_atomic_load(pu + 1, __ATOMIC_RELAXED, __HIP_MEMORY_SCOPE_AGENT);
                a2 = __hip_atomic_load(pu + 2, __ATOMIC_RELAXED, __HIP_MEMORY_SCOPE_AGENT);
                a3 = __hip_atomic_load(pu + 3, __ATOMIC_RELAXED, __HIP_MEMORY_SCOPE_AGENT);
                c0 = __hip_atomic_load(pu + 4, __ATOMIC_RELAXED, __HIP_MEMORY_SCOPE_AGENT);
                c1 = __hip_atomic_load(pu + 5, __ATOMIC_RELAXED, __HIP_MEMORY_SCOPE_AGENT);
                c2 = __hip_atomic_load(pu + 6, __ATOMIC_RELAXED, __HIP_MEMORY_SCOPE_AGENT);
                c3 = __hip_atomic_load(pu + 7, __ATOMIC_RELAXED, __HIP_MEMORY_SCOPE_AGENT);
                if (a0 != SENT && a1 != SENT && a2 != SENT && a3 != SENT &&
                    c0 != SENT && c1 != SENT && c2 != SENT && c3 != SENT) break;
                __builtin_amdgcn_s_sleep(1);
            }
            // scatter: unit u -> xh[u&7][2048 + (u>>3)*8]  (16-B aligned)
            *(uint4*)&xh[u0 & 7][2048 + blku * 8] = make_uint4(a0, a1, a2, a3);
            *(uint4*)&xh[(u0 + 1) & 7][2048 + blku * 8] = make_uint4(c0, c1, c2, c3);
        }
        __syncthreads();   // B2: x + h staged

        f32x4 acc = {0.f, 0.f, 0.f, 0.f};
#pragma unroll
        for (int i = 0; i < 16; ++i) {
            const int kb = ke * 16 + i;
            short8 a = *(const short8*)(arow + (kb << 5));
            short8 b;
            __builtin_memcpy(&b, &w[i], 16);
            acc = __builtin_amdgcn_mfma_f32_16x16x32_bf16(a, b, acc, 0, 0, 0);
        }
        if (lane < 32) *(f32x4*)&red[st][ke][lane][0] = acc;
        __syncthreads();   // B3: partials ready

        // wave 0: poison + fused reduce + gates + publish
        // (waves 1..15 proceed to t+1 x-stage / polling meanwhile)
        if (wave == 0) {
            if (lane < 8) {   // poison own segment of X[(t+2)%3]
                unsigned int* q = bpoi + ((size_t)bx * 8 + lane) * 4;
                __hip_atomic_store(q + 0, SENT, __ATOMIC_RELAXED, __HIP_MEMORY_SCOPE_AGENT);
                __hip_atomic_store(q + 1, SENT, __ATOMIC_RELAXED, __HIP_MEMORY_SCOPE_AGENT);
                __hip_atomic_store(q + 2, SENT, __ATOMIC_RELAXED, __HIP_MEMORY_SCOPE_AGENT);
                __hip_atomic_store(q + 3, SENT, __ATOMIC_RELAXED, __HIP_MEMORY_SCOPE_AGENT);
            }
            const int b = lane >> 3, dl = lane & 7;     // batch, local d
            const int l2b = ((b & 4) << 2) | (dl & 3);  // + g*4 per gate
            const int reg = b & 3;
            const int sst = dl >> 2;
            float z[4];
#pragma unroll
            for (int g = 0; g < 4; ++g) {
                float zz = biasL[g * 8 + dl];
#pragma unroll
                for (int kk = 0; kk < 8; ++kk)
                    zz += red[sst][kk][l2b + g * 4][reg];
                z[g] = zz;
            }
            const float si = fsig(z[0]);
            const float sf = fsig(z[1]);
            const float tg = ftanh(z[2]);
            const float so = fsig(z[3]);
            creg = sf * creg + si * tg;
            const float hval = so * ftanh(creg);
            const float hoth = __shfl_xor(hval, 1, 64);
            const unsigned int pk = (unsigned int)f2b(hval) |
                                    ((unsigned int)f2b(hoth) << 16);
            if ((lane & 1) == 0) {
                // seed own units in next step's LDS image (skip-self path)
                if (t < TT - 1)
                    *(unsigned int*)&xh[b][2048 + d0 + dl] = pk;
            }
            // order poison (issued ~1500 cy ago) before publish; near-free
            __builtin_amdgcn_s_waitcnt(0);
            if ((lane & 1) == 0) {
                unsigned int* hp = bout + ((size_t)bx * 8 + b) * 4 + (dl >> 1);
                __hip_atomic_store(hp, pk, __ATOMIC_RELAXED, __HIP_MEMORY_SCOPE_AGENT);
            }
            // no flag, no post-publish drain: consumers poll the payload
        }
    }
}

// ---------------- final linear: out[b,o] = h[b,:]·w_lin[o,:] + b_lin[o] ----------------
// h (= S_128, in X[128%3] = X2) is in SEGMENTED layout hseg[blk][batch][8].
__global__ void k_final(const unsigned short* __restrict__ h, const float* __restrict__ w_lin,
                        const float* __restrict__ b_lin, float* __restrict__ out) {
    const int wave = threadIdx.x >> 6;
    const int lane = threadIdx.x & 63;
    const int o = blockIdx.x * 4 + wave;
    const float4* w4 = (const float4*)(w_lin + (size_t)o * DD);

    float acc[8];
#pragma unroll
    for (int b = 0; b < 8; ++b) acc[b] = 0.f;
#pragma unroll 2
    for (int it = 0; it < 8; ++it) {
        const int k4 = it * 64 + lane;
        float4 wv = w4[k4];
        const int d = 4 * k4;                         // dims d..d+3, one unit
#pragma unroll
        for (int b = 0; b < 8; ++b) {
            ushort4 hv = *(const ushort4*)(h + ((((size_t)(d >> 3)) * 8 + b) << 3) + (d & 7));
            acc[b] += wv.x * b2f(hv.x) + wv.y * b2f(hv.y) +
                      wv.z * b2f(hv.z) + wv.w * b2f(hv.w);
        }
    }
#pragma unroll
    for (int b = 0; b < 8; ++b) {
        float v = acc[b];
        v += __shfl_xor(v, 32, 64);
        v += __shfl_xor(v, 16, 64);
        v += __shfl_xor(v, 8, 64);
        v += __shfl_xor(v, 4, 64);
        v += __shfl_xor(v, 2, 64);
        v += __shfl_xor(v, 1, 64);
        acc[b] = v;
    }
    if (lane < 8) out[(size_t)lane * NN + o] = acc[lane] + b_lin[o];
}

// ---------------- launch ----------------

extern "C" void kernel_launch(void* const* d_in, const int* in_sizes, int n_in,
                              void* d_out, int out_size, void* d_ws, size_t ws_size,
                              hipStream_t stream) {
    const float* xseq  = (const float*)d_in[0];
    const float* gat_w = (const float*)d_in[1];
    const float* a_src = (const float*)d_in[2];
    const float* a_dst = (const float*)d_in[3];
    const float* g_b   = (const float*)d_in[4];
    const float* w_ih  = (const float*)d_in[5];
    const float* w_hh  = (const float*)d_in[6];
    const float* b_ih  = (const float*)d_in[7];
    const float* b_hh  = (const float*)d_in[8];
    const float* w_lin = (const float*)d_in[9];
    const float* b_lin = (const float*)d_in[10];
    const int*   eidx  = (const int*)d_in[11];
    float* out = (float*)d_out;

    // workspace layout
    unsigned short* seq = (unsigned short*)d_ws;                 // T*B*D bf16 (4 MB)
    unsigned short* WP  = seq + (size_t)TT * BB * DD;            // 64 MB packed weights
    unsigned int* hb    = (unsigned int*)(WP + (size_t)8192 * KTOT); // 3 x 32 KB ring
    int* counts  = (int*)(hb + 3 * 8192);
    int* offs    = counts + NN;
    int* fill    = offs + NN + 1;
    int* csr_src = fill + NN;

    // CSR build
    k_csr_zero<<<1, NN, 0, stream>>>(counts, fill);
    k_csr_count<<<EE / 256, 256, 0, stream>>>(eidx, counts);
    k_csr_scan<<<1, NN, 0, stream>>>(counts, offs);
    k_csr_fill<<<EE / 256, 256, 0, stream>>>(eidx, offs, fill, csr_src);

    // weight pack (bf16, B-frag swizzled)
    k_pack_w<<<16384, 256, 0, stream>>>(w_ih, w_hh, WP);

    // GAT -> seq (bf16)
    k_gat0<<<TT, NN, 0, stream>>>(xseq, gat_w, a_src, a_dst, g_b, offs, csr_src, seq);
    k_gat_rest<<<(TT * 7 * NN) / 256, 256, 0, stream>>>(xseq, gat_w, g_b, seq);

    // init ring: X0 = S_0 zeros, X1/X2 = sentinel (ws poisoned each timed call)
    k_zero<<<96, 256, 0, stream>>>(hb);

    // persistent cooperative LSTM, flag-free sentinel ring
    {
        void* kargs[] = {
            (void*)&seq, (void*)&WP, (void*)&b_ih, (void*)&b_hh, (void*)&hb,
        };
        hipLaunchCooperativeKernel((const void*)k_lstm_persist, dim3(256), dim3(1024),
                                   kargs, 0, stream);
    }

    // final h (S_128) is in ring slot 128%3 == 2, segmented layout
    k_final<<<NN / 4, 256, 0, stream>>>((const unsigned short*)(hb + 2 * 8192),
                                        w_lin, b_lin, out);
}

// Round 4
// 946.795 us; speedup vs baseline: 1.0787x; 1.0787x over previous
//
#include <hip/hip_runtime.h>
#include <hip/hip_cooperative_groups.h>
#include <math.h>

#define BB 8
#define TT 128
#define NN 512
#define HH 4
#define DD 2048      // N*HID
#define EE 16384
#define KTOT 4096    // 2048 (x) + 2048 (h)
#define XROW 4112    // 4096 + 16 pad shorts (32 B) per batch row in LDS

typedef __attribute__((ext_vector_type(8))) short short8;
typedef __attribute__((ext_vector_type(4))) float f32x4;

__device__ __forceinline__ float b2f(unsigned short u) {
    union { unsigned int i; float f; } v; v.i = ((unsigned int)u) << 16; return v.f;
}
__device__ __forceinline__ unsigned short f2b(float f) {
    union { float f; unsigned int i; } v; v.f = f;
    unsigned int r = v.i + 0x7fff + ((v.i >> 16) & 1);
    return (unsigned short)(r >> 16);
}
// fast sigmoid/tanh on v_exp_f32 + v_rcp_f32 (~4 ULP; absmax budget 0.0117)
__device__ __forceinline__ float fsig(float z) {
    return __builtin_amdgcn_rcpf(1.f + __expf(-z));
}
__device__ __forceinline__ float ftanh(float z) {
    return 1.f - 2.f * __builtin_amdgcn_rcpf(1.f + __expf(2.f * z));
}

// ---------------- CSR build: one block, LDS atomics (replaces 4 kernels) ----------------

__global__ __launch_bounds__(1024) void k_csr_build(const int* __restrict__ ei,
                                                    int* __restrict__ offs,
                                                    int* __restrict__ csr_src) {
    __shared__ int cnt[NN];
    __shared__ int off[NN];
    __shared__ int fill[NN];
    const int tid = threadIdx.x;
    if (tid < NN) { cnt[tid] = 0; fill[tid] = 0; }
    __syncthreads();
    for (int e = tid; e < EE; e += 1024) atomicAdd(&cnt[ei[EE + e]], 1);
    __syncthreads();
    if (tid < NN) off[tid] = cnt[tid];
    __syncthreads();
#pragma unroll
    for (int o = 1; o < NN; o <<= 1) {
        int v = 0;
        if (tid < NN && tid >= o) v = off[tid - o];
        __syncthreads();
        if (tid < NN) off[tid] += v;
        __syncthreads();
    }
    if (tid < NN) offs[tid + 1] = off[tid];   // inclusive sums
    if (tid == 0) offs[0] = 0;
    __syncthreads();
    for (int e = tid; e < EE; e += 1024) {
        int d = ei[EE + e];
        int pos = atomicAdd(&fill[d], 1);
        csr_src[(off[d] - cnt[d]) + pos] = ei[e];
    }
}

// ---------------- GAT (outputs bf16 seq[t][b][d]) ----------------

__global__ void k_gat0(const float* __restrict__ xseq, const float* __restrict__ W,
                       const float* __restrict__ as, const float* __restrict__ ad,
                       const float* __restrict__ bias, const int* __restrict__ offs,
                       const int* __restrict__ csr_src, unsigned short* __restrict__ seqout) {
    __shared__ float xr[NN];
    const int t = blockIdx.x;
    const int j = threadIdx.x;
    xr[j] = xseq[t * NN + j];
    __syncthreads();

    const float w0 = W[0], w1 = W[1], w2 = W[2], w3 = W[3];
    const float cs = w0 * as[0] + w1 * as[1] + w2 * as[2] + w3 * as[3];
    const float cd = w0 * ad[0] + w1 * ad[1] + w2 * ad[2] + w3 * ad[3];

    const float xj = xr[j];
    const float ed = cd * xj;
    float e0 = (cs + cd) * xj;
    e0 = e0 > 0.f ? e0 : 0.2f * e0;

    const int s0 = offs[j], s1 = offs[j + 1];
    float m = e0;
    for (int p = s0; p < s1; ++p) {
        float e = cs * xr[csr_src[p]] + ed;
        e = e > 0.f ? e : 0.2f * e;
        m = fmaxf(m, e);
    }
    float den = __expf(e0 - m);
    float num = den * xj;
    for (int p = s0; p < s1; ++p) {
        int s = csr_src[p];
        float e = cs * xr[s] + ed;
        e = e > 0.f ? e : 0.2f * e;
        float wgt = __expf(e - m);
        den += wgt;
        num += wgt * xr[s];
    }
    const float y = num / den;

    ushort4 o;
    o.x = f2b(fmaxf(w0 * y + bias[0], 0.f));
    o.y = f2b(fmaxf(w1 * y + bias[1], 0.f));
    o.z = f2b(fmaxf(w2 * y + bias[2], 0.f));
    o.w = f2b(fmaxf(w3 * y + bias[3], 0.f));
    *(ushort4*)(seqout + (size_t)t * BB * DD + (size_t)j * HH) = o;
}

__global__ void k_gat_rest(const float* __restrict__ xseq, const float* __restrict__ W,
                           const float* __restrict__ bias, unsigned short* __restrict__ seqout) {
    int n = blockIdx.x * blockDim.x + threadIdx.x;
    int t = n / (7 * NN);
    int rem = n - t * (7 * NN);
    int b = 1 + rem / NN;
    int j = rem - (b - 1) * NN;
    float x = xseq[((size_t)b * TT + t) * NN + j];
    const float w0 = W[0], w1 = W[1], w2 = W[2], w3 = W[3];
    ushort4 o;
    o.x = f2b(fmaxf(w0 * x + bias[0], 0.f));
    o.y = f2b(fmaxf(w1 * x + bias[1], 0.f));
    o.z = f2b(fmaxf(w2 * x + bias[2], 0.f));
    o.w = f2b(fmaxf(w3 * x + bias[3], 0.f));
    *(ushort4*)(seqout + (size_t)t * BB * DD + (size_t)b * DD + (size_t)j * HH) = o;
}

// ---------------- zero h buffers + barrier flags ----------------

__global__ void k_zero(unsigned int* __restrict__ hb, unsigned int* __restrict__ bar) {
    int i = blockIdx.x * blockDim.x + threadIdx.x;
    if (i < 16384) hb[i] = 0u;     // hb0 + hb1 (64 KB)
    if (i < 256) bar[i] = 0u;      // dense flags
}

// ---------------- persistent LSTM ----------------
// 256 blocks x 1024 thr (cooperative). Block b: d0=8b..8b+7, strips 2b/2b+1.
// Wave (st=w>>3, ke=w&7). SPLIT ROLES:
//   x-waves (ke<4): self-stage their own 8-batch x k-range [512ke,512ke+512)
//     with normal cached loads, run their 16 MFMAs immediately (no dependency
//     on h, hidden under the h-wait). Wave-local LDS -> no barrier needed.
//   h-waves (ke>=4): wave4 polls the 256 flags (R1-proven protocol), posts an
//     LDS generation word `go`; all h-waves then cooperatively stage h via
//     8-B agent loads (8/lane), sync via LDS arrival counter `cnt`, and run
//     the h-half MFMAs.
// One __syncthreads per step; red[] is parity ping-ponged so wave0's gate
// reads of step t can't race step-t+1 writes. Weights are loaded + converted
// f32->bf16 fragments in-kernel (k_pack_w eliminated).
// FIX vs R3: consumer-side lane decomposition of the B-fragment is
// quad = lane>>4, n = lane&15 (k_pack_w STORED at quad*16+n; reading at
// `lane` inverts that). R3 used the producer decomposition -> wrong weights.
__global__ __launch_bounds__(1024, 4) void k_lstm_persist(
    const unsigned short* __restrict__ seq,
    const float* __restrict__ wih, const float* __restrict__ whh,
    const float* __restrict__ b_ih, const float* __restrict__ b_hh,
    unsigned short* __restrict__ hb0, unsigned short* __restrict__ hb1,
    unsigned int* __restrict__ flags) {
    __shared__ unsigned short xh[8][XROW];  // 65792 B x||h image
    __shared__ float red[2][2][8][32][4];   // 16 KB, parity ping-pong
    __shared__ float biasL[32];
    __shared__ int go;                      // h-wave release generation
    __shared__ int cnt;                     // h-stage arrivals (8 per step)

    const int tid = threadIdx.x;
    const int wave = tid >> 6, lane = tid & 63;
    const int st = wave >> 3, ke = wave & 7;
    const bool is_h = (ke >= 4);
    const int bx = blockIdx.x;
    const int d0 = bx * 8;

    if (tid == 0) { go = 0; cnt = 0; }
    if (tid < 32) {
        const int row = (tid >> 3) * 2048 + d0 + (tid & 7);
        biasL[tid] = b_ih[row] + b_hh[row];
    }

    // load + convert this wave's 16 weight B-fragments (f32 -> bf16, once)
    uint4 w[16];
    {
        const int n = lane & 15, quad = lane >> 4;            // consumer mapping
        const int row = (n >> 2) * 2048 + d0 + 4 * st + (n & 3);
#pragma unroll
        for (int i = 0; i < 16; ++i) {
            const int k = (ke * 16 + i) * 32 + quad * 8;
            const float* src = (k < 2048 ? wih : whh) + (size_t)row * 2048 + (k & 2047);
            float4 f0 = *(const float4*)src;
            float4 f1 = *(const float4*)(src + 4);
            w[i] = make_uint4(
                (unsigned int)f2b(f0.x) | ((unsigned int)f2b(f0.y) << 16),
                (unsigned int)f2b(f0.z) | ((unsigned int)f2b(f0.w) << 16),
                (unsigned int)f2b(f1.x) | ((unsigned int)f2b(f1.y) << 16),
                (unsigned int)f2b(f1.z) | ((unsigned int)f2b(f1.w) << 16));
        }
    }
    __syncthreads();   // init (go/cnt/biasL) visible

    // A-operand LDS read base: batch = lane&7, quad = lane>>4
    const unsigned short* arow = &xh[lane & 7][(lane >> 4) << 3];
    // h-thread id (h-waves only): 8 waves x 64 lanes = 512
    const int ht = ((st << 2) | (ke & 3)) * 64 + lane;

    float creg = 0.f;   // wave0 gate state: cell (b=lane>>3, d=d0+(lane&7))

    for (int t = 0; t < TT; ++t) {
        const unsigned short* xt = seq + (size_t)t * BB * DD;
        const unsigned short* hin = (t & 1) ? hb1 : hb0;
        unsigned short* hout = (t & 1) ? hb0 : hb1;

        if (!is_h) {
            // x-wave: self-stage own region (shorts [512ke,512ke+512) x 8 batches)
            const unsigned short* base = xt + 512 * ke + 8 * lane;
            uint4 xv[8];
#pragma unroll
            for (int j = 0; j < 8; ++j) xv[j] = *(const uint4*)(base + (size_t)j * DD);
#pragma unroll
            for (int j = 0; j < 8; ++j) *(uint4*)&xh[j][512 * ke + 8 * lane] = xv[j];
            // wave-local: ds_write -> ds_read ordered (same-wave LDS in order)
        } else {
            if (t > 0) {
                if (wave == 4) {   // one wave polls the 256 global flags
                    while (true) {
                        bool ok = true;
#pragma unroll
                        for (int j2 = 0; j2 < 4; ++j2) {
                            unsigned int v = __hip_atomic_load(&flags[j2 * 64 + lane],
                                                               __ATOMIC_RELAXED,
                                                               __HIP_MEMORY_SCOPE_AGENT);
                            ok &= (v >= (unsigned int)t);
                        }
                        if (__all(ok)) break;
                        __builtin_amdgcn_s_sleep(1);
                    }
                    if (lane == 0)
                        __hip_atomic_store(&go, t, __ATOMIC_RELEASE,
                                           __HIP_MEMORY_SCOPE_WORKGROUP);
                } else {           // other h-waves: cheap LDS spin
                    while (__hip_atomic_load(&go, __ATOMIC_ACQUIRE,
                                             __HIP_MEMORY_SCOPE_WORKGROUP) < t) {}
                }
            }
            // stage h cooperatively: 8 x 8-B agent loads per lane (coalesced)
            const unsigned long long* hq = (const unsigned long long*)hin;
            unsigned long long hv[8];
#pragma unroll
            for (int i = 0; i < 8; ++i)
                hv[i] = __hip_atomic_load(&hq[i * 512 + ht], __ATOMIC_RELAXED,
                                          __HIP_MEMORY_SCOPE_AGENT);
#pragma unroll
            for (int i = 0; i < 8; ++i) {
                const int q = i * 512 + ht;            // qword in h image
                ((unsigned long long*)&xh[q >> 9][2048])[q & 511] = hv[i];
            }
            __threadfence_block();
            if (lane == 0) atomicAdd(&cnt, 1);
            const int target = 8 * (t + 1);
            while (__hip_atomic_load(&cnt, __ATOMIC_ACQUIRE,
                                     __HIP_MEMORY_SCOPE_WORKGROUP) < target) {}
        }

        f32x4 acc = {0.f, 0.f, 0.f, 0.f};
#pragma unroll
        for (int i = 0; i < 16; ++i) {
            short8 a = *(const short8*)(arow + ((ke * 16 + i) << 5));
            short8 b;
            __builtin_memcpy(&b, &w[i], 16);
            acc = __builtin_amdgcn_mfma_f32_16x16x32_bf16(a, b, acc, 0, 0, 0);
        }
        if (lane < 32) *(f32x4*)&red[t & 1][st][ke][lane][0] = acc;
        __syncthreads();   // ONE barrier per step: partials ready

        // wave 0 (an x-wave): fused reduce + gates + publish; other waves
        // run ahead into step t+1 (x-waves compute, h-waves poll).
        if (wave == 0) {
            const int b = lane >> 3, dl = lane & 7;
            const int l2b = ((b & 4) << 2) | (dl & 3);
            const int reg = b & 3;
            const int sst = dl >> 2;
            float z[4];
#pragma unroll
            for (int g = 0; g < 4; ++g) {
                float zz = biasL[g * 8 + dl];
#pragma unroll
                for (int kk = 0; kk < 8; ++kk)
                    zz += red[t & 1][sst][kk][l2b + g * 4][reg];
                z[g] = zz;
            }
            const float si = fsig(z[0]);
            const float sf = fsig(z[1]);
            const float tg = ftanh(z[2]);
            const float so = fsig(z[3]);
            creg = sf * creg + si * tg;
            const float hval = so * ftanh(creg);
            const float hoth = __shfl_xor(hval, 1, 64);
            if ((lane & 1) == 0) {
                const unsigned int pk = (unsigned int)f2b(hval) |
                                        ((unsigned int)f2b(hoth) << 16);
                unsigned int* hp = (unsigned int*)(hout + (size_t)b * DD + d0) + (dl >> 1);
                __hip_atomic_store(hp, pk, __ATOMIC_RELAXED, __HIP_MEMORY_SCOPE_AGENT);
            }
            if (t != TT - 1) {
                __builtin_amdgcn_s_waitcnt(0);   // drain h stores to coherence pt
                if (lane == 0)
                    __hip_atomic_store(&flags[bx], (unsigned int)(t + 1),
                                       __ATOMIC_RELAXED, __HIP_MEMORY_SCOPE_AGENT);
            }
        }
    }
}

// ---------------- final linear: out[b,o] = h[b,:]·w_lin[o,:] + b_lin[o] ----------------
__global__ void k_final(const unsigned short* __restrict__ h, const float* __restrict__ w_lin,
                        const float* __restrict__ b_lin, float* __restrict__ out) {
    const int wave = threadIdx.x >> 6;
    const int lane = threadIdx.x & 63;
    const int o = blockIdx.x * 4 + wave;
    const float4* w4 = (const float4*)(w_lin + (size_t)o * DD);

    float acc[8];
#pragma unroll
    for (int b = 0; b < 8; ++b) acc[b] = 0.f;
#pragma unroll 2
    for (int it = 0; it < 8; ++it) {
        const int k4 = it * 64 + lane;
        float4 wv = w4[k4];
#pragma unroll
        for (int b = 0; b < 8; ++b) {
            ushort4 hv = *(const ushort4*)(h + (size_t)b * DD + 4 * (size_t)k4);
            acc[b] += wv.x * b2f(hv.x) + wv.y * b2f(hv.y) +
                      wv.z * b2f(hv.z) + wv.w * b2f(hv.w);
        }
    }
#pragma unroll
    for (int b = 0; b < 8; ++b) {
        float v = acc[b];
        v += __shfl_xor(v, 32, 64);
        v += __shfl_xor(v, 16, 64);
        v += __shfl_xor(v, 8, 64);
        v += __shfl_xor(v, 4, 64);
        v += __shfl_xor(v, 2, 64);
        v += __shfl_xor(v, 1, 64);
        acc[b] = v;
    }
    if (lane < 8) out[(size_t)lane * NN + o] = acc[lane] + b_lin[o];
}

// ---------------- launch ----------------

extern "C" void kernel_launch(void* const* d_in, const int* in_sizes, int n_in,
                              void* d_out, int out_size, void* d_ws, size_t ws_size,
                              hipStream_t stream) {
    const float* xseq  = (const float*)d_in[0];
    const float* gat_w = (const float*)d_in[1];
    const float* a_src = (const float*)d_in[2];
    const float* a_dst = (const float*)d_in[3];
    const float* g_b   = (const float*)d_in[4];
    const float* w_ih  = (const float*)d_in[5];
    const float* w_hh  = (const float*)d_in[6];
    const float* b_ih  = (const float*)d_in[7];
    const float* b_hh  = (const float*)d_in[8];
    const float* w_lin = (const float*)d_in[9];
    const float* b_lin = (const float*)d_in[10];
    const int*   eidx  = (const int*)d_in[11];
    float* out = (float*)d_out;

    // workspace layout (no packed-weight buffer anymore)
    unsigned short* seq = (unsigned short*)d_ws;                 // T*B*D bf16 (4 MB)
    unsigned short* hb0 = seq + (size_t)TT * BB * DD;            // B*D bf16
    unsigned short* hb1 = hb0 + BB * DD;                         // B*D bf16
    unsigned int* flags = (unsigned int*)(hb1 + BB * DD);        // 256 dwords
    int* offs    = (int*)(flags + 256);
    int* csr_src = offs + NN + 1;

    // CSR build (single block, LDS atomics)
    k_csr_build<<<1, 1024, 0, stream>>>(eidx, offs, csr_src);

    // GAT -> seq (bf16)
    k_gat0<<<TT, NN, 0, stream>>>(xseq, gat_w, a_src, a_dst, g_b, offs, csr_src, seq);
    k_gat_rest<<<(TT * 7 * NN) / 256, 256, 0, stream>>>(xseq, gat_w, g_b, seq);

    // zero h buffers + flags (ws poisoned each timed call)
    k_zero<<<64, 256, 0, stream>>>((unsigned int*)hb0, flags);

    // persistent cooperative LSTM (x/h wave split, single barrier per step)
    {
        void* kargs[] = {
            (void*)&seq, (void*)&w_ih, (void*)&w_hh, (void*)&b_ih, (void*)&b_hh,
            (void*)&hb0, (void*)&hb1, (void*)&flags,
        };
        hipLaunchCooperativeKernel((const void*)k_lstm_persist, dim3(256), dim3(1024),
                                   kargs, 0, stream);
    }

    // final h is in hb0 after 128 steps (t=127 writes hout=hb0)
    k_final<<<NN / 4, 256, 0, stream>>>(hb0, w_lin, b_lin, out);
}

// Round 5
// 733.868 us; speedup vs baseline: 1.3916x; 1.2901x over previous
//
#include <hip/hip_runtime.h>
#include <hip/hip_cooperative_groups.h>
#include <math.h>

#define BB 8
#define TT 128
#define NN 512
#define HH 4
#define DD 2048      // N*HID
#define EE 16384
#define KTOT 4096    // 2048 (x) + 2048 (h)
#define NKB 128      // KTOT/32 kblocks
#define XROW 4112    // 4096 + 16 pad shorts (32 B) per batch row in LDS

typedef __attribute__((ext_vector_type(8))) short short8;
typedef __attribute__((ext_vector_type(4))) float f32x4;

__device__ __forceinline__ float b2f(unsigned short u) {
    union { unsigned int i; float f; } v; v.i = ((unsigned int)u) << 16; return v.f;
}
__device__ __forceinline__ unsigned short f2b(float f) {
    union { float f; unsigned int i; } v; v.f = f;
    unsigned int r = v.i + 0x7fff + ((v.i >> 16) & 1);
    return (unsigned short)(r >> 16);
}
// fast sigmoid/tanh on v_exp_f32 + v_rcp_f32 (~4 ULP; absmax budget 0.0117;
// proven in R2/R4: absmax unchanged at 0.01171875)
__device__ __forceinline__ float fsig(float z) {
    return __builtin_amdgcn_rcpf(1.f + __expf(-z));
}
__device__ __forceinline__ float ftanh(float z) {
    return 1.f - 2.f * __builtin_amdgcn_rcpf(1.f + __expf(2.f * z));
}

// ------- CSR build (one block, LDS atomics) + h/flag zero folded in -------

__global__ __launch_bounds__(1024) void k_csr_build(const int* __restrict__ ei,
                                                    int* __restrict__ offs,
                                                    int* __restrict__ csr_src,
                                                    unsigned int* __restrict__ hb,
                                                    unsigned int* __restrict__ bar) {
    __shared__ int cnt[NN];
    __shared__ int off[NN];
    __shared__ int fill[NN];
    const int tid = threadIdx.x;
    // zero h buffers (hb0+hb1 = 16384 dwords) + 256 flags (ws poisoned per call)
    for (int i = tid; i < 16384; i += 1024) hb[i] = 0u;
    if (tid < 256) bar[tid] = 0u;
    if (tid < NN) { cnt[tid] = 0; fill[tid] = 0; }
    __syncthreads();
    for (int e = tid; e < EE; e += 1024) atomicAdd(&cnt[ei[EE + e]], 1);
    __syncthreads();
    if (tid < NN) off[tid] = cnt[tid];
    __syncthreads();
#pragma unroll
    for (int o = 1; o < NN; o <<= 1) {
        int v = 0;
        if (tid < NN && tid >= o) v = off[tid - o];
        __syncthreads();
        if (tid < NN) off[tid] += v;
        __syncthreads();
    }
    if (tid < NN) offs[tid + 1] = off[tid];   // inclusive sums
    if (tid == 0) offs[0] = 0;
    __syncthreads();
    for (int e = tid; e < EE; e += 1024) {
        int d = ei[EE + e];
        int pos = atomicAdd(&fill[d], 1);
        csr_src[(off[d] - cnt[d]) + pos] = ei[e];
    }
}

// ---------------- GAT (outputs bf16 seq[t][b][d]) ----------------

__global__ void k_gat0(const float* __restrict__ xseq, const float* __restrict__ W,
                       const float* __restrict__ as, const float* __restrict__ ad,
                       const float* __restrict__ bias, const int* __restrict__ offs,
                       const int* __restrict__ csr_src, unsigned short* __restrict__ seqout) {
    __shared__ float xr[NN];
    const int t = blockIdx.x;
    const int j = threadIdx.x;
    xr[j] = xseq[t * NN + j];
    __syncthreads();

    const float w0 = W[0], w1 = W[1], w2 = W[2], w3 = W[3];
    const float cs = w0 * as[0] + w1 * as[1] + w2 * as[2] + w3 * as[3];
    const float cd = w0 * ad[0] + w1 * ad[1] + w2 * ad[2] + w3 * ad[3];

    const float xj = xr[j];
    const float ed = cd * xj;
    float e0 = (cs + cd) * xj;
    e0 = e0 > 0.f ? e0 : 0.2f * e0;

    const int s0 = offs[j], s1 = offs[j + 1];
    float m = e0;
    for (int p = s0; p < s1; ++p) {
        float e = cs * xr[csr_src[p]] + ed;
        e = e > 0.f ? e : 0.2f * e;
        m = fmaxf(m, e);
    }
    float den = __expf(e0 - m);
    float num = den * xj;
    for (int p = s0; p < s1; ++p) {
        int s = csr_src[p];
        float e = cs * xr[s] + ed;
        e = e > 0.f ? e : 0.2f * e;
        float wgt = __expf(e - m);
        den += wgt;
        num += wgt * xr[s];
    }
    const float y = num / den;

    ushort4 o;
    o.x = f2b(fmaxf(w0 * y + bias[0], 0.f));
    o.y = f2b(fmaxf(w1 * y + bias[1], 0.f));
    o.z = f2b(fmaxf(w2 * y + bias[2], 0.f));
    o.w = f2b(fmaxf(w3 * y + bias[3], 0.f));
    *(ushort4*)(seqout + (size_t)t * BB * DD + (size_t)j * HH) = o;
}

__global__ void k_gat_rest(const float* __restrict__ xseq, const float* __restrict__ W,
                           const float* __restrict__ bias, unsigned short* __restrict__ seqout) {
    int n = blockIdx.x * blockDim.x + threadIdx.x;
    int t = n / (7 * NN);
    int rem = n - t * (7 * NN);
    int b = 1 + rem / NN;
    int j = rem - (b - 1) * NN;
    float x = xseq[((size_t)b * TT + t) * NN + j];
    const float w0 = W[0], w1 = W[1], w2 = W[2], w3 = W[3];
    ushort4 o;
    o.x = f2b(fmaxf(w0 * x + bias[0], 0.f));
    o.y = f2b(fmaxf(w1 * x + bias[1], 0.f));
    o.z = f2b(fmaxf(w2 * x + bias[2], 0.f));
    o.w = f2b(fmaxf(w3 * x + bias[3], 0.f));
    *(ushort4*)(seqout + (size_t)t * BB * DD + (size_t)b * DD + (size_t)j * HH) = o;
}

// ---------------- weight pack: f32 -> bf16 B-fragment tiles ----------------
__global__ __launch_bounds__(256) void k_pack_w(const float* __restrict__ wih,
                                                const float* __restrict__ whh,
                                                unsigned short* __restrict__ WP) {
    const int pair = blockIdx.x * 4 + (threadIdx.x >> 6);  // (s,kb): 0..65535
    const int lane = threadIdx.x & 63;
    const int s = pair >> 7, kb = pair & 127;
    const int n = lane >> 2, quad = lane & 3;
    const int d = (s >> 1) * 8 + (s & 1) * 4 + (n & 3);
    const int row = (n >> 2) * 2048 + d;
    const int k = kb * 32 + quad * 8;
    const float* src = (k < 2048) ? (wih + (size_t)row * 2048 + k)
                                  : (whh + (size_t)row * 2048 + (k - 2048));
    unsigned int u[4];
#pragma unroll
    for (int p = 0; p < 4; ++p)
        u[p] = (unsigned int)f2b(src[2 * p]) | ((unsigned int)f2b(src[2 * p + 1]) << 16);
    ((uint4*)WP)[(size_t)pair * 64 + quad * 16 + n] = make_uint4(u[0], u[1], u[2], u[3]);
}

// ---------------- persistent LSTM (R1 structure — measured best) ----------------
// 256 blocks x 1024 thr (cooperative). Block b: d0=8b..8b+7, strips 2b (st=0)
// and 2b+1 (st=1). Wave (st=w>>3, ke=w&7) holds 16 weight B-frags in regs,
// loaded ONCE from the packed buffer. 128 timesteps in-kernel. All cross-block
// traffic (h, flags) agent-scope sc1. Deltas vs the 486 µs R1 kernel:
//   * gates use v_exp_f32-based fsig/ftanh (libm expf/tanhf was ~1 kcy on the
//     serial chain)
//   * h publish: 16 x 8-B agent stores (was 32 x 4-B) via one extra shfl
//   * h staging: 4 x 8-B agent loads/thread (was 8 x 4-B)
__global__ __launch_bounds__(1024, 4) void k_lstm_persist(
    const unsigned short* __restrict__ seq, const uint4* __restrict__ WPq,
    const float* __restrict__ b_ih, const float* __restrict__ b_hh,
    unsigned short* __restrict__ hb0, unsigned short* __restrict__ hb1,
    unsigned int* __restrict__ flags) {
    __shared__ unsigned short xh[8][XROW];  // 65792 B unique x||h image
    __shared__ float red[2][8][32][4];      // 8 KB k-partial D
    __shared__ float biasL[32];

    const int tid = threadIdx.x;
    const int wave = tid >> 6, lane = tid & 63;
    const int st = wave >> 3, ke = wave & 7;
    const int d0 = blockIdx.x * 8;
    const size_t sglob = (size_t)blockIdx.x * 2 + st;

    if (tid < 32) {
        const int g = tid >> 3, dl = tid & 7;
        const int row = g * 2048 + d0 + dl;
        biasL[tid] = b_ih[row] + b_hh[row];
    }

    // load this wave's 16 weight fragments into registers (once)
    uint4 w[16];
    {
        const uint4* wp = WPq + (sglob * NKB + (size_t)ke * 16) * 64 + lane;
#pragma unroll
        for (int i = 0; i < 16; ++i) w[i] = wp[i * 64];
    }

    // A-operand LDS read base for this lane: batch = lane&7, quad = lane>>4
    const unsigned short* arow = &xh[lane & 7][(lane >> 4) << 3];

    // gate-thread state (wave 0, lane = 8*b + dl): one c cell per lane
    float creg = 0.f;

    for (int t = 0; t < TT; ++t) {
        const unsigned short* xt = seq + (size_t)t * BB * DD;
        const unsigned short* hin = (t & 1) ? hb1 : hb0;
        unsigned short* hout = (t & 1) ? hb0 : hb1;

        // stage x part (k<2048), two-phase; overlaps the flag wait below
        uint4 xv[2];
#pragma unroll
        for (int i = 0; i < 2; ++i) {
            const int c = tid + 1024 * i;            // 2048 chunks of 16 B
            xv[i] = *(const uint4*)(xt + (c >> 8) * DD + ((c & 255) << 3));
        }
#pragma unroll
        for (int i = 0; i < 2; ++i) {
            const int c = tid + 1024 * i;
            *(uint4*)&xh[c >> 8][(c & 255) << 3] = xv[i];
        }

        // one-hop barrier: wave 0 polls all 256 dense flags (4 coalesced
        // dword loads per lane -> 16 L3 line-requests per round)
        if (t > 0 && wave == 0) {
            const unsigned int gen = (unsigned int)t;
            while (true) {
                bool okl = true;
#pragma unroll
                for (int j = 0; j < 4; ++j) {
                    unsigned int v = __hip_atomic_load(&flags[j * 64 + lane],
                                                       __ATOMIC_RELAXED,
                                                       __HIP_MEMORY_SCOPE_AGENT);
                    okl &= (v >= gen);
                }
                if (__all(okl)) break;
                __builtin_amdgcn_s_sleep(1);
            }
        }
        __syncthreads();   // B1: flags passed -> h in L3 is step t-1 data

        // stage h part (k>=2048): two-phase, 4 x 8-B agent loads in flight
        const unsigned long long* hq = (const unsigned long long*)hin;
        unsigned long long hv[4];
#pragma unroll
        for (int i = 0; i < 4; ++i)
            hv[i] = __hip_atomic_load(&hq[tid + 1024 * i], __ATOMIC_RELAXED,
                                      __HIP_MEMORY_SCOPE_AGENT);
#pragma unroll
        for (int i = 0; i < 4; ++i) {
            const int q = tid + 1024 * i;            // 4096 qwords, 512/batch
            ((unsigned long long*)&xh[q >> 9][2048])[q & 511] = hv[i];
        }
        __syncthreads();   // B2: x+h staged

        f32x4 acc = {0.f, 0.f, 0.f, 0.f};
#pragma unroll
        for (int i = 0; i < 16; ++i) {
            const int kb = ke * 16 + i;
            short8 a = *(const short8*)(arow + (kb << 5));
            short8 b;
            __builtin_memcpy(&b, &w[i], 16);
            acc = __builtin_amdgcn_mfma_f32_16x16x32_bf16(a, b, acc, 0, 0, 0);
        }
        if (lane < 32) *(f32x4*)&red[st][ke][lane][0] = acc;
        __syncthreads();   // B3: partials ready

        // wave 0: fused reduce + gates + publish (others proceed to t+1 x-stage
        // and then wait at B1 until wave0 arrives -> red reuse is race-free)
        if (wave == 0) {
            const int b = lane >> 3, dl = lane & 7;     // batch, local d
            const int l2b = ((b & 4) << 2) | (dl & 3);  // + g*4 per gate
            const int reg = b & 3;
            const int sst = dl >> 2;
            float z[4];
#pragma unroll
            for (int g = 0; g < 4; ++g) {
                float zz = biasL[g * 8 + dl];
#pragma unroll
                for (int kk = 0; kk < 8; ++kk)
                    zz += red[sst][kk][l2b + g * 4][reg];
                z[g] = zz;
            }
            const float si = fsig(z[0]);
            const float sf = fsig(z[1]);
            const float tg = ftanh(z[2]);
            const float so = fsig(z[3]);
            creg = sf * creg + si * tg;
            const float hval = so * ftanh(creg);
            const float hoth = __shfl_xor(hval, 1, 64);
            // even-dl lanes: pk = dims (dl, dl+1)
            const unsigned int pk = (unsigned int)f2b(hval) |
                                    ((unsigned int)f2b(hoth) << 16);
            const unsigned int pko = __shfl_xor(pk, 2, 64);  // dl0<-dl2, dl4<-dl6
            if ((lane & 3) == 0) {    // dl in {0,4}: publish dims dl..dl+3 (8 B)
                const unsigned long long v =
                    (unsigned long long)pk | ((unsigned long long)pko << 32);
                __hip_atomic_store((unsigned long long*)(hout + (size_t)b * DD + d0 + dl),
                                   v, __ATOMIC_RELAXED, __HIP_MEMORY_SCOPE_AGENT);
            }
            if (t != TT - 1) {
                __builtin_amdgcn_s_waitcnt(0);   // h stores at coherence point (L3)
                if (lane == 0)
                    __hip_atomic_store(&flags[blockIdx.x], (unsigned int)(t + 1),
                                       __ATOMIC_RELAXED, __HIP_MEMORY_SCOPE_AGENT);
            }
        }
    }
}

// ---------------- final linear: out[b,o] = h[b,:]·w_lin[o,:] + b_lin[o] ----------------
__global__ void k_final(const unsigned short* __restrict__ h, const float* __restrict__ w_lin,
                        const float* __restrict__ b_lin, float* __restrict__ out) {
    const int wave = threadIdx.x >> 6;
    const int lane = threadIdx.x & 63;
    const int o = blockIdx.x * 4 + wave;
    const float4* w4 = (const float4*)(w_lin + (size_t)o * DD);

    float acc[8];
#pragma unroll
    for (int b = 0; b < 8; ++b) acc[b] = 0.f;
#pragma unroll 2
    for (int it = 0; it < 8; ++it) {
        const int k4 = it * 64 + lane;
        float4 wv = w4[k4];
#pragma unroll
        for (int b = 0; b < 8; ++b) {
            ushort4 hv = *(const ushort4*)(h + (size_t)b * DD + 4 * (size_t)k4);
            acc[b] += wv.x * b2f(hv.x) + wv.y * b2f(hv.y) +
                      wv.z * b2f(hv.z) + wv.w * b2f(hv.w);
        }
    }
#pragma unroll
    for (int b = 0; b < 8; ++b) {
        float v = acc[b];
        v += __shfl_xor(v, 32, 64);
        v += __shfl_xor(v, 16, 64);
        v += __shfl_xor(v, 8, 64);
        v += __shfl_xor(v, 4, 64);
        v += __shfl_xor(v, 2, 64);
        v += __shfl_xor(v, 1, 64);
        acc[b] = v;
    }
    if (lane < 8) out[(size_t)lane * NN + o] = acc[lane] + b_lin[o];
}

// ---------------- launch ----------------

extern "C" void kernel_launch(void* const* d_in, const int* in_sizes, int n_in,
                              void* d_out, int out_size, void* d_ws, size_t ws_size,
                              hipStream_t stream) {
    const float* xseq  = (const float*)d_in[0];
    const float* gat_w = (const float*)d_in[1];
    const float* a_src = (const float*)d_in[2];
    const float* a_dst = (const float*)d_in[3];
    const float* g_b   = (const float*)d_in[4];
    const float* w_ih  = (const float*)d_in[5];
    const float* w_hh  = (const float*)d_in[6];
    const float* b_ih  = (const float*)d_in[7];
    const float* b_hh  = (const float*)d_in[8];
    const float* w_lin = (const float*)d_in[9];
    const float* b_lin = (const float*)d_in[10];
    const int*   eidx  = (const int*)d_in[11];
    float* out = (float*)d_out;

    // workspace layout
    unsigned short* seq = (unsigned short*)d_ws;                 // T*B*D bf16 (4 MB)
    unsigned short* WP  = seq + (size_t)TT * BB * DD;            // 64 MB packed weights
    unsigned short* hb0 = WP + (size_t)8192 * KTOT;              // B*D bf16
    unsigned short* hb1 = hb0 + BB * DD;                         // B*D bf16
    unsigned int* flags = (unsigned int*)(hb1 + BB * DD);        // 256 dwords (dense)
    int* offs    = (int*)(flags + 256);
    int* csr_src = offs + NN + 1;

    // CSR build + h/flag zero (single block, LDS atomics)
    k_csr_build<<<1, 1024, 0, stream>>>(eidx, offs, csr_src,
                                        (unsigned int*)hb0, flags);

    // weight pack (bf16, B-frag swizzled; coalesced — off the critical chain)
    k_pack_w<<<16384, 256, 0, stream>>>(w_ih, w_hh, WP);

    // GAT -> seq (bf16)
    k_gat0<<<TT, NN, 0, stream>>>(xseq, gat_w, a_src, a_dst, g_b, offs, csr_src, seq);
    k_gat_rest<<<(TT * 7 * NN) / 256, 256, 0, stream>>>(xseq, gat_w, g_b, seq);

    // persistent cooperative LSTM with fence-free agent-scope flag barrier
    {
        void* kargs[] = {
            (void*)&seq, (void*)&WP, (void*)&b_ih, (void*)&b_hh,
            (void*)&hb0, (void*)&hb1, (void*)&flags,
        };
        hipLaunchCooperativeKernel((const void*)k_lstm_persist, dim3(256), dim3(1024),
                                   kargs, 0, stream);
    }

    // final h is in hb0 after 128 steps (t=127 writes hout=hb0)
    k_final<<<NN / 4, 256, 0, stream>>>(hb0, w_lin, b_lin, out);
}